// Round 5
// baseline (232.369 us; speedup 1.0000x reference)
//
#include <hip/hip_runtime.h>

// GraphProjection: out[N,963] = concat(verts[N,3], proj(f0)[N,64], proj(f1)[N,128],
//                                      proj(f2)[N,256], proj(f3)[N,512])
// Degenerate "bilinear": weights collapse to w11 = (x2-x1)*(y2-y1) in {0,1};
// every feature element is a masked gather of feat[c, floor(x), floor(y)].
//
// V6: persistent wave-per-row with 2-row software pipelining.
//  - 2048 blocks (8192 waves) grid-stride over rows; each loop iteration
//    processes TWO independent rows: all gather loads issued before any
//    store -> 2x memory-level parallelism, cross-row ILP, no per-row wave
//    teardown. Attacks the latency-bound serial chain
//    (vert load -> fdiv -> level_off -> gather -> store).
//  - x4 grid anchored at col 3: region boundaries {3,67,195,451} are ==3
//    (mod 4), slice bases >=256B aligned -> all loads aligned dwordx4.
//  - plain stores (NT measured -25us in V4); stores dwordx4 at 4B align.
//  - params computed inline per wave (wave-uniform, readfirstlane -> SGPR).

static constexpr int NV      = 50000;
static constexpr int TOTAL   = 963 * NV;          // 48,150,000

// transposed feature sizes (floats): [S*S, C]
static constexpr int T0 = 56 * 56 * 64;   // 200,704
static constexpr int T1 = 28 * 28 * 128;  // 100,352
static constexpr int T2 = 14 * 14 * 256;  // 50,176
static constexpr int T3 = 7 * 7 * 512;    // 25,088
static constexpr int TSUM = T0 + T1 + T2 + T3; // 376,320
static constexpr int ZN   = 516;          // zero block (>=512 needed)

typedef float f32x4 __attribute__((ext_vector_type(4)));

__device__ __forceinline__ void store4_u(float* p, f32x4 v) {
  __builtin_memcpy(p, &v, 16);  // 4B-aligned dwordx4 store
}

__device__ __forceinline__ int level_off(float h, float w, float scale, int S) {
  float x = h * scale;  // scale = S/224 is an exact power of two
  float y = w * scale;
  int x1 = (int)floorf(x);
  int x2 = min((int)ceilf(x), S - 1);
  int y1 = (int)floorf(y);
  int y2 = min((int)ceilf(y), S - 1);
  return (x2 > x1 && y2 > y1) ? (x1 * S + y1) : -1;
}

// [C,S,S] -> [S*S, C] so per-wave channel reads are contiguous; also zero-fills
// the ZN-float zero block used for out-of-image vertices.
__global__ __launch_bounds__(256) void transpose_k(
    const float* __restrict__ f0, const float* __restrict__ f1,
    const float* __restrict__ f2, const float* __restrict__ f3,
    float* __restrict__ t0, float* __restrict__ t1,
    float* __restrict__ t2, float* __restrict__ t3,
    float* __restrict__ zeros) {
  int i = blockIdx.x * 256 + threadIdx.x;
  if (i < T0) { int off = i >> 6, c = i & 63;  t0[i] = f0[c * 3136 + off]; return; }
  i -= T0;
  if (i < T1) { int off = i >> 7, c = i & 127; t1[i] = f1[c * 784 + off];  return; }
  i -= T1;
  if (i < T2) { int off = i >> 8, c = i & 255; t2[i] = f2[c * 196 + off];  return; }
  i -= T2;
  if (i < T3) { int off = i >> 9, c = i & 511; t3[i] = f3[c * 49 + off];   return; }
  i -= T3;
  if (i < ZN) zeros[i] = 0.0f;
}

struct RowPtrs {
  const float* s0; const float* s1; const float* s2; const float* s3;
  float v0, v1, v2;
};

__device__ __forceinline__ RowPtrs make_row(
    int n, const float* __restrict__ verts,
    const float* __restrict__ t0, const float* __restrict__ t1,
    const float* __restrict__ t2, const float* __restrict__ t3,
    const float* __restrict__ zeros) {
  RowPtrs r;
  r.v0 = verts[3 * n + 0];
  r.v1 = verts[3 * n + 1];
  r.v2 = verts[3 * n + 2];
  // match numpy fp32 exactly: no FMA contraction, IEEE rn division
  float h = __fadd_rn(__fmul_rn(248.0f, __fdiv_rn(r.v1, r.v2)), 111.5f);
  float w = __fadd_rn(__fmul_rn(248.0f, __fdiv_rn(r.v0, -r.v2)), 111.5f);
  h = fminf(fmaxf(h, 0.0f), 223.0f);
  w = fminf(fmaxf(w, 0.0f), 223.0f);
  int p0 = __builtin_amdgcn_readfirstlane(level_off(h, w, 0.25f,    56));
  int p1 = __builtin_amdgcn_readfirstlane(level_off(h, w, 0.125f,   28));
  int p2 = __builtin_amdgcn_readfirstlane(level_off(h, w, 0.0625f,  14));
  int p3 = __builtin_amdgcn_readfirstlane(level_off(h, w, 0.03125f, 7));
  // p<0 redirects into the zero block; offsets keep 16B alignment on the
  // x4 grid since (col - start_r) == 0 (mod 4).
  r.s0 = ((p0 >= 0) ? t0 + (p0 << 6) : zeros) - 3;
  r.s1 = ((p1 >= 0) ? t1 + (p1 << 7) : zeros) - 67;
  r.s2 = ((p2 >= 0) ? t2 + (p2 << 8) : zeros) - 195;
  r.s3 = ((p3 >= 0) ? t3 + (p3 << 9) : zeros) - 451;
  return r;
}

// lane-dependent column/base helpers (x4 grid anchored at col 3)
__device__ __forceinline__ void row_loads(const RowPtrs& r, int lane,
                                          f32x4& a, f32x4& b, f32x4& c, f32x4& d) {
  int col0 = 3 + 4 * lane;            // [3,259): t0|t1|t2
  int col1 = 259 + 4 * lane;          // [259,515): t2|t3
  int col2 = 515 + 4 * lane;          // [515,771): t3
  int col3 = 771 + 4 * lane;          // [771,963) lane<48: t3
  const float* b0 = (lane < 16) ? r.s0 : (lane < 48) ? r.s1 : r.s2;
  const float* b1 = (lane < 48) ? r.s2 : r.s3;
  a = *reinterpret_cast<const f32x4*>(b0 + col0);
  b = *reinterpret_cast<const f32x4*>(b1 + col1);
  c = *reinterpret_cast<const f32x4*>(r.s3 + col2);
  if (lane < 48) d = *reinterpret_cast<const f32x4*>(r.s3 + col3);
}

__device__ __forceinline__ void row_stores(const RowPtrs& r, int lane, float* o,
                                           f32x4 a, f32x4 b, f32x4 c, f32x4 d) {
  if (lane < 3) o[lane] = (lane == 0) ? r.v0 : (lane == 1) ? r.v1 : r.v2;
  store4_u(o + 3 + 4 * lane, a);
  store4_u(o + 259 + 4 * lane, b);
  store4_u(o + 515 + 4 * lane, c);
  if (lane < 48) store4_u(o + 771 + 4 * lane, d);
}

// Persistent wave-per-row, 2 rows per iteration for MLP/ILP.
__global__ __launch_bounds__(256) void gp_row_k(
    const float* __restrict__ verts,
    const float* __restrict__ t0, const float* __restrict__ t1,
    const float* __restrict__ t2, const float* __restrict__ t3,
    const float* __restrict__ zeros,
    float* __restrict__ out) {
  const int nWaves = (int)(gridDim.x * 4);           // blocks * 256 / 64
  const int wave0  = (blockIdx.x * 256 + threadIdx.x) >> 6;
  const int lane   = threadIdx.x & 63;

  for (int n = wave0; n < NV; n += 2 * nWaves) {
    const int n2 = n + nWaves;
    const bool has2 = (n2 < NV);

    RowPtrs rA = make_row(n, verts, t0, t1, t2, t3, zeros);
    RowPtrs rB;
    if (has2) rB = make_row(n2, verts, t0, t1, t2, t3, zeros);

    f32x4 a0, a1, a2, a3, b0, b1, b2, b3;
    row_loads(rA, lane, a0, a1, a2, a3);
    if (has2) row_loads(rB, lane, b0, b1, b2, b3);

    row_stores(rA, lane, out + 963 * n, a0, a1, a2, a3);
    if (has2) row_stores(rB, lane, out + 963 * n2, b0, b1, b2, b3);
  }
}

// ---------- fallback paths (small workspace) ----------
__device__ __forceinline__ void proj_hw(const float* __restrict__ verts, int n,
                                        float& h, float& w) {
  float v0 = verts[3 * n + 0];
  float v1 = verts[3 * n + 1];
  float v2 = verts[3 * n + 2];
  h = __fadd_rn(__fmul_rn(248.0f, __fdiv_rn(v1, v2)), 111.5f);
  w = __fadd_rn(__fmul_rn(248.0f, __fdiv_rn(v0, -v2)), 111.5f);
  h = fminf(fmaxf(h, 0.0f), 223.0f);
  w = fminf(fmaxf(w, 0.0f), 223.0f);
}

template <int MODE>
__device__ __forceinline__ int get_off(const int* __restrict__ params,
                                       const float* __restrict__ verts,
                                       int n, int k, float scale, int S) {
  if (MODE < 2) return params[4 * n + k];
  float h, w;
  proj_hw(verts, n, h, w);
  return level_off(h, w, scale, S);
}

__global__ __launch_bounds__(256) void prep_params_k(const float* __restrict__ verts,
                                                     int* __restrict__ params) {
  int n = blockIdx.x * 256 + threadIdx.x;
  if (n >= NV) return;
  float h, w;
  proj_hw(verts, n, h, w);
  params[4 * n + 0] = level_off(h, w, 0.25f,    56);
  params[4 * n + 1] = level_off(h, w, 0.125f,   28);
  params[4 * n + 2] = level_off(h, w, 0.0625f,  14);
  params[4 * n + 3] = level_off(h, w, 0.03125f, 7);
}

static constexpr int B_VERTS = 3 * NV;            // 150,000
static constexpr int B_F0    = B_VERTS + 64 * NV; // 3,350,000
static constexpr int B_F1    = B_F0 + 128 * NV;   // 9,750,000
static constexpr int B_F2    = B_F1 + 256 * NV;   // 22,550,000

template <int MODE>
__global__ __launch_bounds__(256) void gp_main_k(
    const float* __restrict__ verts,
    const float* __restrict__ f0, const float* __restrict__ f1,
    const float* __restrict__ f2, const float* __restrict__ f3,
    const int* __restrict__ params, float* __restrict__ out) {
  int j = blockIdx.x * 256 + threadIdx.x;
  if (j >= TOTAL) return;

  if (j < B_VERTS) {
    int n = j / 3;
    int col = j - 3 * n;
    out[n * 963 + col] = verts[j];
    return;
  }

  int n, outcol;
  float val = 0.0f;
  if (j < B_F0) {
    int t = j - B_VERTS; n = t >> 6; int c = t & 63;
    int off = get_off<MODE>(params, verts, n, 0, 0.25f, 56);
    if (off >= 0) val = f0[c * 3136 + off];
    outcol = 3 + c;
  } else if (j < B_F1) {
    int t = j - B_F0; n = t >> 7; int c = t & 127;
    int off = get_off<MODE>(params, verts, n, 1, 0.125f, 28);
    if (off >= 0) val = f1[c * 784 + off];
    outcol = 67 + c;
  } else if (j < B_F2) {
    int t = j - B_F1; n = t >> 8; int c = t & 255;
    int off = get_off<MODE>(params, verts, n, 2, 0.0625f, 14);
    if (off >= 0) val = f2[c * 196 + off];
    outcol = 195 + c;
  } else {
    int t = j - B_F2; n = t >> 9; int c = t & 511;
    int off = get_off<MODE>(params, verts, n, 3, 0.03125f, 7);
    if (off >= 0) val = f3[c * 49 + off];
    outcol = 451 + c;
  }
  out[n * 963 + outcol] = val;
}

extern "C" void kernel_launch(void* const* d_in, const int* in_sizes, int n_in,
                              void* d_out, int out_size, void* d_ws, size_t ws_size,
                              hipStream_t stream) {
  const float* f0    = (const float*)d_in[0];
  const float* f1    = (const float*)d_in[1];
  const float* f2    = (const float*)d_in[2];
  const float* f3    = (const float*)d_in[3];
  const float* verts = (const float*)d_in[4];
  float* out = (float*)d_out;

  const size_t PARAM_BYTES = (size_t)NV * 4 * sizeof(int);        // 800,000
  const size_t FAST_BYTES  = (size_t)(TSUM + ZN) * sizeof(float); // 1,507,344

  if (ws_size >= FAST_BYTES) {
    float* t0 = (float*)d_ws;
    float* t1 = t0 + T0;
    float* t2 = t1 + T1;
    float* t3 = t2 + T2;
    float* zeros = t3 + T3;
    transpose_k<<<(TSUM + ZN + 255) / 256, 256, 0, stream>>>(f0, f1, f2, f3,
                                                             t0, t1, t2, t3, zeros);
    gp_row_k<<<2048, 256, 0, stream>>>(verts, t0, t1, t2, t3, zeros, out);
  } else if (ws_size >= PARAM_BYTES) {
    int* params = (int*)d_ws;
    prep_params_k<<<(NV + 255) / 256, 256, 0, stream>>>(verts, params);
    gp_main_k<1><<<(TOTAL + 255) / 256, 256, 0, stream>>>(verts, f0, f1, f2, f3, params, out);
  } else {
    gp_main_k<2><<<(TOTAL + 255) / 256, 256, 0, stream>>>(verts, f0, f1, f2, f3, nullptr, out);
  }
}

// Round 7
// 226.388 us; speedup vs baseline: 1.0264x; 1.0264x over previous
//
#include <hip/hip_runtime.h>

// GraphProjection: out[N,963] = concat(verts[N,3], proj(f0)[N,64], proj(f1)[N,128],
//                                      proj(f2)[N,256], proj(f3)[N,512])
// Degenerate "bilinear": weights collapse to w11 = (x2-x1)*(y2-y1) in {0,1};
// every feature element is a masked gather of feat[c, floor(x), floor(y)].
//
// V7 (resubmit after infra failure): block-staged writer (fill-identical
// write stream).
//  - 512-thread block owns 16 consecutive rows: 16*963 floats = 61,632 B,
//    exactly 963 cache lines -> block output span is 64B line-aligned.
//  - Phase 1 (gather): each wave loads 2 rows' x4 gathers (8-9 dwordx4 in
//    flight, 2x V5 MLP) and stages them into LDS with row stride 976 floats
//    (3904 B, 64B-aligned; +1 float data offset makes every x4 chunk land
//    16B-aligned -> ds_write_b128, conflict-free).
//  - Phase 2 (store): after barrier, block streams LDS -> out as flat
//    16B-aligned dwordx4 stores; 4 lanes = one full 64B line. Write side is
//    now decoupled from gather latency and bit-identical in shape to the
//    6.7 TB/s fill kernel.
//  - plain stores (NT measured -25us in V4); params inline per wave.

static constexpr int NV      = 50000;
static constexpr int TOTAL   = 963 * NV;          // 48,150,000

// transposed feature sizes (floats): [S*S, C]
static constexpr int T0 = 56 * 56 * 64;   // 200,704
static constexpr int T1 = 28 * 28 * 128;  // 100,352
static constexpr int T2 = 14 * 14 * 256;  // 50,176
static constexpr int T3 = 7 * 7 * 512;    // 25,088
static constexpr int TSUM = T0 + T1 + T2 + T3; // 376,320
static constexpr int ZN   = 516;          // zero block (>=512 needed)

static constexpr int RPB  = 16;   // rows per block (50000 = 3125 * 16 exactly)
static constexpr int BT   = 512;  // threads per block (8 waves, 2 rows/wave)
static constexpr int LROW = 976;  // LDS row stride in floats (3904 B, 64B-aligned)

typedef float f32x4 __attribute__((ext_vector_type(4)));

__device__ __forceinline__ void store4_u(float* p, f32x4 v) {
  __builtin_memcpy(p, &v, 16);  // 16B-aligned here -> global_store_dwordx4
}

// g / 963, exact for 0 <= g < 48,150,000 (M = ceil(2^41/963))
__device__ __forceinline__ int div963(int g) {
  return (int)(((unsigned long long)(unsigned)g * 2283513246ull) >> 41);
}

__device__ __forceinline__ int level_off(float h, float w, float scale, int S) {
  float x = h * scale;  // scale = S/224 is an exact power of two
  float y = w * scale;
  int x1 = (int)floorf(x);
  int x2 = min((int)ceilf(x), S - 1);
  int y1 = (int)floorf(y);
  int y2 = min((int)ceilf(y), S - 1);
  return (x2 > x1 && y2 > y1) ? (x1 * S + y1) : -1;
}

// [C,S,S] -> [S*S, C] so per-wave channel reads are contiguous; also zero-fills
// the ZN-float zero block used for out-of-image vertices.
__global__ __launch_bounds__(256) void transpose_k(
    const float* __restrict__ f0, const float* __restrict__ f1,
    const float* __restrict__ f2, const float* __restrict__ f3,
    float* __restrict__ t0, float* __restrict__ t1,
    float* __restrict__ t2, float* __restrict__ t3,
    float* __restrict__ zeros) {
  int i = blockIdx.x * 256 + threadIdx.x;
  if (i < T0) { int off = i >> 6, c = i & 63;  t0[i] = f0[c * 3136 + off]; return; }
  i -= T0;
  if (i < T1) { int off = i >> 7, c = i & 127; t1[i] = f1[c * 784 + off];  return; }
  i -= T1;
  if (i < T2) { int off = i >> 8, c = i & 255; t2[i] = f2[c * 196 + off];  return; }
  i -= T2;
  if (i < T3) { int off = i >> 9, c = i & 511; t3[i] = f3[c * 49 + off];   return; }
  i -= T3;
  if (i < ZN) zeros[i] = 0.0f;
}

struct RowPtrs {
  const float* s0; const float* s1; const float* s2; const float* s3;
  float v0, v1, v2;
};

__device__ __forceinline__ RowPtrs make_row(
    int n, const float* __restrict__ verts,
    const float* __restrict__ t0, const float* __restrict__ t1,
    const float* __restrict__ t2, const float* __restrict__ t3,
    const float* __restrict__ zeros) {
  RowPtrs r;
  r.v0 = verts[3 * n + 0];
  r.v1 = verts[3 * n + 1];
  r.v2 = verts[3 * n + 2];
  // match numpy fp32 exactly: no FMA contraction, IEEE rn division
  float h = __fadd_rn(__fmul_rn(248.0f, __fdiv_rn(r.v1, r.v2)), 111.5f);
  float w = __fadd_rn(__fmul_rn(248.0f, __fdiv_rn(r.v0, -r.v2)), 111.5f);
  h = fminf(fmaxf(h, 0.0f), 223.0f);
  w = fminf(fmaxf(w, 0.0f), 223.0f);
  int p0 = __builtin_amdgcn_readfirstlane(level_off(h, w, 0.25f,    56));
  int p1 = __builtin_amdgcn_readfirstlane(level_off(h, w, 0.125f,   28));
  int p2 = __builtin_amdgcn_readfirstlane(level_off(h, w, 0.0625f,  14));
  int p3 = __builtin_amdgcn_readfirstlane(level_off(h, w, 0.03125f, 7));
  // p<0 redirects into the zero block; offsets keep 16B alignment on the
  // x4 grid since (col - start_r) == 0 (mod 4).
  r.s0 = ((p0 >= 0) ? t0 + (p0 << 6) : zeros) - 3;
  r.s1 = ((p1 >= 0) ? t1 + (p1 << 7) : zeros) - 67;
  r.s2 = ((p2 >= 0) ? t2 + (p2 << 8) : zeros) - 195;
  r.s3 = ((p3 >= 0) ? t3 + (p3 << 9) : zeros) - 451;
  return r;
}

// x4 grid anchored at col 3; region boundaries {3,67,195,451} are ==3 (mod 4),
// slice bases >=256B aligned -> all loads aligned global_load_dwordx4.
__device__ __forceinline__ void row_loads(const RowPtrs& r, int lane,
                                          f32x4& a, f32x4& b, f32x4& c, f32x4& d) {
  int col0 = 3 + 4 * lane;            // [3,259): t0|t1|t2
  int col1 = 259 + 4 * lane;          // [259,515): t2|t3
  int col2 = 515 + 4 * lane;          // [515,771): t3
  int col3 = 771 + 4 * lane;          // [771,963) lane<48: t3
  const float* b0 = (lane < 16) ? r.s0 : (lane < 48) ? r.s1 : r.s2;
  const float* b1 = (lane < 48) ? r.s2 : r.s3;
  a = *reinterpret_cast<const f32x4*>(b0 + col0);
  b = *reinterpret_cast<const f32x4*>(b1 + col1);
  c = *reinterpret_cast<const f32x4*>(r.s3 + col2);
  if (lane < 48) d = *reinterpret_cast<const f32x4*>(r.s3 + col3);
}

__device__ __forceinline__ void row_to_lds(float* L, const RowPtrs& r, int lane,
                                           f32x4 a, f32x4 b, f32x4 c, f32x4 d) {
  // L points at col 0 of this row's LDS image; L+col is 16B-aligned for
  // col == 3 (mod 4) because the row image starts at float offset r*976+1.
  if (lane < 3) L[lane] = (lane == 0) ? r.v0 : (lane == 1) ? r.v1 : r.v2;
  *reinterpret_cast<f32x4*>(L + 3 + 4 * lane)   = a;
  *reinterpret_cast<f32x4*>(L + 259 + 4 * lane) = b;
  *reinterpret_cast<f32x4*>(L + 515 + 4 * lane) = c;
  if (lane < 48) *reinterpret_cast<f32x4*>(L + 771 + 4 * lane) = d;
}

// Block-staged: 16 rows gathered into LDS, then streamed out as a flat,
// line-aligned dwordx4 sequence (fill-kernel-shaped write stream).
__global__ __launch_bounds__(BT) void gp_block_k(
    const float* __restrict__ verts,
    const float* __restrict__ t0, const float* __restrict__ t1,
    const float* __restrict__ t2, const float* __restrict__ t3,
    const float* __restrict__ zeros,
    float* __restrict__ out) {
  __shared__ float lds[RPB * LROW];  // 62,464 B

  const int wave  = threadIdx.x >> 6;  // 0..7
  const int lane  = threadIdx.x & 63;
  const int rbase = blockIdx.x * RPB;

  // ---- gather phase: wave handles rows 2*wave and 2*wave+1 ----
  {
    const int rA = 2 * wave, rB = rA + 1;
    RowPtrs pA = make_row(rbase + rA, verts, t0, t1, t2, t3, zeros);
    RowPtrs pB = make_row(rbase + rB, verts, t0, t1, t2, t3, zeros);
    f32x4 a0, a1, a2, a3, b0, b1, b2, b3;
    row_loads(pA, lane, a0, a1, a2, a3);   // 8-9 loads in flight before any
    row_loads(pB, lane, b0, b1, b2, b3);   // LDS write waits on them
    row_to_lds(lds + rA * LROW + 1, pA, lane, a0, a1, a2, a3);
    row_to_lds(lds + rB * LROW + 1, pB, lane, b0, b1, b2, b3);
  }
  __syncthreads();

  // ---- store phase: 16*963 = 15,408 floats = 3,852 x4 chunks ----
  float* o = out + (size_t)rbase * 963;    // byte offset blockIdx*61632, 64B-aligned
#pragma unroll
  for (int it = 0; it < 8; ++it) {
    int k = it * BT + (int)threadIdx.x;    // chunk id
    if (k < 3852) {
      int g0 = 4 * k;
      f32x4 v;
#pragma unroll
      for (int j = 0; j < 4; ++j) {        // j compile-time after unroll
        int g = g0 + j;                    // block-local float index
        int r = div963(g);
        int c = g - 963 * r;
        v[j] = lds[r * LROW + 1 + c];
      }
      store4_u(o + g0, v);                 // 16B-aligned; 4 lanes = full line
    }
  }
}

// ---------- fallback paths (small workspace) ----------
__device__ __forceinline__ void proj_hw(const float* __restrict__ verts, int n,
                                        float& h, float& w) {
  float v0 = verts[3 * n + 0];
  float v1 = verts[3 * n + 1];
  float v2 = verts[3 * n + 2];
  h = __fadd_rn(__fmul_rn(248.0f, __fdiv_rn(v1, v2)), 111.5f);
  w = __fadd_rn(__fmul_rn(248.0f, __fdiv_rn(v0, -v2)), 111.5f);
  h = fminf(fmaxf(h, 0.0f), 223.0f);
  w = fminf(fmaxf(w, 0.0f), 223.0f);
}

template <int MODE>
__device__ __forceinline__ int get_off(const int* __restrict__ params,
                                       const float* __restrict__ verts,
                                       int n, int k, float scale, int S) {
  if (MODE < 2) return params[4 * n + k];
  float h, w;
  proj_hw(verts, n, h, w);
  return level_off(h, w, scale, S);
}

__global__ __launch_bounds__(256) void prep_params_k(const float* __restrict__ verts,
                                                     int* __restrict__ params) {
  int n = blockIdx.x * 256 + threadIdx.x;
  if (n >= NV) return;
  float h, w;
  proj_hw(verts, n, h, w);
  params[4 * n + 0] = level_off(h, w, 0.25f,    56);
  params[4 * n + 1] = level_off(h, w, 0.125f,   28);
  params[4 * n + 2] = level_off(h, w, 0.0625f,  14);
  params[4 * n + 3] = level_off(h, w, 0.03125f, 7);
}

static constexpr int B_VERTS = 3 * NV;            // 150,000
static constexpr int B_F0    = B_VERTS + 64 * NV; // 3,350,000
static constexpr int B_F1    = B_F0 + 128 * NV;   // 9,750,000
static constexpr int B_F2    = B_F1 + 256 * NV;   // 22,550,000

template <int MODE>
__global__ __launch_bounds__(256) void gp_main_k(
    const float* __restrict__ verts,
    const float* __restrict__ f0, const float* __restrict__ f1,
    const float* __restrict__ f2, const float* __restrict__ f3,
    const int* __restrict__ params, float* __restrict__ out) {
  int j = blockIdx.x * 256 + threadIdx.x;
  if (j >= TOTAL) return;

  if (j < B_VERTS) {
    int n = j / 3;
    int col = j - 3 * n;
    out[n * 963 + col] = verts[j];
    return;
  }

  int n, outcol;
  float val = 0.0f;
  if (j < B_F0) {
    int t = j - B_VERTS; n = t >> 6; int c = t & 63;
    int off = get_off<MODE>(params, verts, n, 0, 0.25f, 56);
    if (off >= 0) val = f0[c * 3136 + off];
    outcol = 3 + c;
  } else if (j < B_F1) {
    int t = j - B_F0; n = t >> 7; int c = t & 127;
    int off = get_off<MODE>(params, verts, n, 1, 0.125f, 28);
    if (off >= 0) val = f1[c * 784 + off];
    outcol = 67 + c;
  } else if (j < B_F2) {
    int t = j - B_F1; n = t >> 8; int c = t & 255;
    int off = get_off<MODE>(params, verts, n, 2, 0.0625f, 14);
    if (off >= 0) val = f2[c * 196 + off];
    outcol = 195 + c;
  } else {
    int t = j - B_F2; n = t >> 9; int c = t & 511;
    int off = get_off<MODE>(params, verts, n, 3, 0.03125f, 7);
    if (off >= 0) val = f3[c * 49 + off];
    outcol = 451 + c;
  }
  out[n * 963 + outcol] = val;
}

extern "C" void kernel_launch(void* const* d_in, const int* in_sizes, int n_in,
                              void* d_out, int out_size, void* d_ws, size_t ws_size,
                              hipStream_t stream) {
  const float* f0    = (const float*)d_in[0];
  const float* f1    = (const float*)d_in[1];
  const float* f2    = (const float*)d_in[2];
  const float* f3    = (const float*)d_in[3];
  const float* verts = (const float*)d_in[4];
  float* out = (float*)d_out;

  const size_t PARAM_BYTES = (size_t)NV * 4 * sizeof(int);        // 800,000
  const size_t FAST_BYTES  = (size_t)(TSUM + ZN) * sizeof(float); // 1,507,344

  if (ws_size >= FAST_BYTES) {
    float* t0 = (float*)d_ws;
    float* t1 = t0 + T0;
    float* t2 = t1 + T1;
    float* t3 = t2 + T2;
    float* zeros = t3 + T3;
    transpose_k<<<(TSUM + ZN + 255) / 256, 256, 0, stream>>>(f0, f1, f2, f3,
                                                             t0, t1, t2, t3, zeros);
    gp_block_k<<<NV / RPB, BT, 0, stream>>>(verts, t0, t1, t2, t3, zeros, out);
  } else if (ws_size >= PARAM_BYTES) {
    int* params = (int*)d_ws;
    prep_params_k<<<(NV + 255) / 256, 256, 0, stream>>>(verts, params);
    gp_main_k<1><<<(TOTAL + 255) / 256, 256, 0, stream>>>(verts, f0, f1, f2, f3, params, out);
  } else {
    gp_main_k<2><<<(TOTAL + 255) / 256, 256, 0, stream>>>(verts, f0, f1, f2, f3, nullptr, out);
  }
}

// Round 8
// 202.787 us; speedup vs baseline: 1.1459x; 1.1164x over previous
//
#include <hip/hip_runtime.h>

// GraphProjection: out[N,963] = concat(verts[N,3], proj(f0)[N,64], proj(f1)[N,128],
//                                      proj(f2)[N,256], proj(f3)[N,512])
// Degenerate "bilinear": weights collapse to w11 = (x2-x1)*(y2-y1) in {0,1};
// every feature element is a masked gather of feat[c, floor(x), floor(y)].
//
// V8: V5 (wave-per-row, x4 both sides) + precomputed params fetched via a
// wave-uniform scalar load. Theory: V5's per-wave serial prefix
// (verts load -> 2x fdiv -> level_off -> readfirstlane, ~500-1000 cy) gates
// the first gather of every one of 50,000 short-lived waves and halves
// memory-pipe utilization. Moving the projection math to the 3us prep
// kernel reduces the prefix to one s_load_dwordx4 + 4 pointer selects.
//  - x4 grid anchored at col 3: boundaries {3,67,195,451} are ==3 (mod 4),
//    slice bases >=256B aligned -> all loads aligned dwordx4.
//  - plain stores (NT measured -25us in V4); stores dwordx4 at 4B align.

static constexpr int NV      = 50000;
static constexpr int TOTAL   = 963 * NV;          // 48,150,000

// transposed feature sizes (floats): [S*S, C]
static constexpr int T0 = 56 * 56 * 64;   // 200,704
static constexpr int T1 = 28 * 28 * 128;  // 100,352
static constexpr int T2 = 14 * 14 * 256;  // 50,176
static constexpr int T3 = 7 * 7 * 512;    // 25,088
static constexpr int TSUM = T0 + T1 + T2 + T3; // 376,320
static constexpr int ZN   = 516;          // zero block (>=512 needed)

typedef float f32x4 __attribute__((ext_vector_type(4)));

__device__ __forceinline__ void store4_u(float* p, f32x4 v) {
  __builtin_memcpy(p, &v, 16);  // 4B-aligned dwordx4 store
}

__device__ __forceinline__ void proj_hw(const float* __restrict__ verts, int n,
                                        float& h, float& w) {
  float v0 = verts[3 * n + 0];
  float v1 = verts[3 * n + 1];
  float v2 = verts[3 * n + 2];
  // match numpy fp32 exactly: no FMA contraction, IEEE rn division
  h = __fadd_rn(__fmul_rn(248.0f, __fdiv_rn(v1, v2)), 111.5f);
  w = __fadd_rn(__fmul_rn(248.0f, __fdiv_rn(v0, -v2)), 111.5f);
  h = fminf(fmaxf(h, 0.0f), 223.0f);
  w = fminf(fmaxf(w, 0.0f), 223.0f);
}

__device__ __forceinline__ int level_off(float h, float w, float scale, int S) {
  float x = h * scale;  // scale = S/224 is an exact power of two
  float y = w * scale;
  int x1 = (int)floorf(x);
  int x2 = min((int)ceilf(x), S - 1);
  int y1 = (int)floorf(y);
  int y2 = min((int)ceilf(y), S - 1);
  return (x2 > x1 && y2 > y1) ? (x1 * S + y1) : -1;
}

__global__ __launch_bounds__(256) void prep_params_k(const float* __restrict__ verts,
                                                     int* __restrict__ params) {
  int n = blockIdx.x * 256 + threadIdx.x;
  if (n >= NV) return;
  float h, w;
  proj_hw(verts, n, h, w);
  params[4 * n + 0] = level_off(h, w, 0.25f,    56);
  params[4 * n + 1] = level_off(h, w, 0.125f,   28);
  params[4 * n + 2] = level_off(h, w, 0.0625f,  14);
  params[4 * n + 3] = level_off(h, w, 0.03125f, 7);
}

// [C,S,S] -> [S*S, C] so per-wave channel reads are contiguous; also zero-fills
// the ZN-float zero block used for out-of-image vertices.
__global__ __launch_bounds__(256) void transpose_k(
    const float* __restrict__ f0, const float* __restrict__ f1,
    const float* __restrict__ f2, const float* __restrict__ f3,
    float* __restrict__ t0, float* __restrict__ t1,
    float* __restrict__ t2, float* __restrict__ t3,
    float* __restrict__ zeros) {
  int i = blockIdx.x * 256 + threadIdx.x;
  if (i < T0) { int off = i >> 6, c = i & 63;  t0[i] = f0[c * 3136 + off]; return; }
  i -= T0;
  if (i < T1) { int off = i >> 7, c = i & 127; t1[i] = f1[c * 784 + off];  return; }
  i -= T1;
  if (i < T2) { int off = i >> 8, c = i & 255; t2[i] = f2[c * 196 + off];  return; }
  i -= T2;
  if (i < T3) { int off = i >> 9, c = i & 511; t3[i] = f3[c * 49 + off];   return; }
  i -= T3;
  if (i < ZN) zeros[i] = 0.0f;
}

// Wave-per-vertex: 64 lanes copy one 963-dword output row with x4 accesses.
// Cols [0,3)=verts, [3,67)=t0, [67,195)=t1, [195,451)=t2, [451,963)=t3.
// Prefix is one wave-uniform s_load_dwordx4 of params + pointer selects.
__global__ __launch_bounds__(256) void gp_row_k(
    const float* __restrict__ verts,
    const float* __restrict__ t0, const float* __restrict__ t1,
    const float* __restrict__ t2, const float* __restrict__ t3,
    const float* __restrict__ zeros,
    const int* __restrict__ params,
    float* __restrict__ out) {
  int wid  = (blockIdx.x * 256 + threadIdx.x) >> 6;
  int lane = threadIdx.x & 63;
  if (wid >= NV) return;
  const int n = __builtin_amdgcn_readfirstlane(wid);  // wave-uniform -> SGPR

  // head elements: issue the (vector) verts load for lanes 0..2 immediately
  float hv = 0.0f;
  if (lane < 3) hv = verts[3 * n + lane];

  // wave-uniform param fetch: uniform address -> s_load_dwordx4 (scalar cache)
  int4 pv = *reinterpret_cast<const int4*>(params + 4 * n);
  int p0 = __builtin_amdgcn_readfirstlane(pv.x);
  int p1 = __builtin_amdgcn_readfirstlane(pv.y);
  int p2 = __builtin_amdgcn_readfirstlane(pv.z);
  int p3 = __builtin_amdgcn_readfirstlane(pv.w);

  // p<0 redirects into the zero block; offsets keep 16B alignment on the
  // x4 grid since (col - start_r) == 0 (mod 4).
  const float* s0 = ((p0 >= 0) ? t0 + (p0 << 6) : zeros) - 3;
  const float* s1 = ((p1 >= 0) ? t1 + (p1 << 7) : zeros) - 67;
  const float* s2 = ((p2 >= 0) ? t2 + (p2 << 8) : zeros) - 195;
  const float* s3 = ((p3 >= 0) ? t3 + (p3 << 9) : zeros) - 451;

  float* o = out + 963 * n;

  // all gathers issued back-to-back (aligned dwordx4)
  int col0 = 3 + 4 * lane;            // [3,259): t0|t1|t2
  int col1 = 259 + 4 * lane;          // [259,515): t2|t3
  int col2 = 515 + 4 * lane;          // [515,771): t3
  int col3 = 771 + 4 * lane;          // [771,963) lane<48: t3
  const float* b0 = (lane < 16) ? s0 : (lane < 48) ? s1 : s2;
  const float* b1 = (lane < 48) ? s2 : s3;
  f32x4 a = *reinterpret_cast<const f32x4*>(b0 + col0);
  f32x4 b = *reinterpret_cast<const f32x4*>(b1 + col1);
  f32x4 c = *reinterpret_cast<const f32x4*>(s3 + col2);
  f32x4 d;
  if (lane < 48) d = *reinterpret_cast<const f32x4*>(s3 + col3);

  if (lane < 3) o[lane] = hv;
  store4_u(o + col0, a);
  store4_u(o + col1, b);
  store4_u(o + col2, c);
  if (lane < 48) store4_u(o + col3, d);
}

// ---------- fallback paths (small workspace) ----------
template <int MODE>
__device__ __forceinline__ int get_off(const int* __restrict__ params,
                                       const float* __restrict__ verts,
                                       int n, int k, float scale, int S) {
  if (MODE < 2) return params[4 * n + k];
  float h, w;
  proj_hw(verts, n, h, w);
  return level_off(h, w, scale, S);
}

static constexpr int B_VERTS = 3 * NV;            // 150,000
static constexpr int B_F0    = B_VERTS + 64 * NV; // 3,350,000
static constexpr int B_F1    = B_F0 + 128 * NV;   // 9,750,000
static constexpr int B_F2    = B_F1 + 256 * NV;   // 22,550,000

template <int MODE>
__global__ __launch_bounds__(256) void gp_main_k(
    const float* __restrict__ verts,
    const float* __restrict__ f0, const float* __restrict__ f1,
    const float* __restrict__ f2, const float* __restrict__ f3,
    const int* __restrict__ params, float* __restrict__ out) {
  int j = blockIdx.x * 256 + threadIdx.x;
  if (j >= TOTAL) return;

  if (j < B_VERTS) {
    int n = j / 3;
    int col = j - 3 * n;
    out[n * 963 + col] = verts[j];
    return;
  }

  int n, outcol;
  float val = 0.0f;
  if (j < B_F0) {
    int t = j - B_VERTS; n = t >> 6; int c = t & 63;
    int off = get_off<MODE>(params, verts, n, 0, 0.25f, 56);
    if (off >= 0) val = f0[c * 3136 + off];
    outcol = 3 + c;
  } else if (j < B_F1) {
    int t = j - B_F0; n = t >> 7; int c = t & 127;
    int off = get_off<MODE>(params, verts, n, 1, 0.125f, 28);
    if (off >= 0) val = f1[c * 784 + off];
    outcol = 67 + c;
  } else if (j < B_F2) {
    int t = j - B_F1; n = t >> 8; int c = t & 255;
    int off = get_off<MODE>(params, verts, n, 2, 0.0625f, 14);
    if (off >= 0) val = f2[c * 196 + off];
    outcol = 195 + c;
  } else {
    int t = j - B_F2; n = t >> 9; int c = t & 511;
    int off = get_off<MODE>(params, verts, n, 3, 0.03125f, 7);
    if (off >= 0) val = f3[c * 49 + off];
    outcol = 451 + c;
  }
  out[n * 963 + outcol] = val;
}

extern "C" void kernel_launch(void* const* d_in, const int* in_sizes, int n_in,
                              void* d_out, int out_size, void* d_ws, size_t ws_size,
                              hipStream_t stream) {
  const float* f0    = (const float*)d_in[0];
  const float* f1    = (const float*)d_in[1];
  const float* f2    = (const float*)d_in[2];
  const float* f3    = (const float*)d_in[3];
  const float* verts = (const float*)d_in[4];
  float* out = (float*)d_out;

  const size_t PARAM_BYTES = (size_t)NV * 4 * sizeof(int);  // 800,000 (16B-aligned)
  const size_t FULL_BYTES  = PARAM_BYTES + (size_t)(TSUM + ZN) * sizeof(float);

  if (ws_size >= FULL_BYTES) {
    int*   params = (int*)d_ws;
    float* t0 = (float*)((char*)d_ws + PARAM_BYTES);
    float* t1 = t0 + T0;
    float* t2 = t1 + T1;
    float* t3 = t2 + T2;
    float* zeros = t3 + T3;
    prep_params_k<<<(NV + 255) / 256, 256, 0, stream>>>(verts, params);
    transpose_k<<<(TSUM + ZN + 255) / 256, 256, 0, stream>>>(f0, f1, f2, f3,
                                                             t0, t1, t2, t3, zeros);
    const int rowBlocks = (NV * 64 + 255) / 256;  // 12,500 (one wave per vertex)
    gp_row_k<<<rowBlocks, 256, 0, stream>>>(verts, t0, t1, t2, t3, zeros, params, out);
  } else if (ws_size >= PARAM_BYTES) {
    int* params = (int*)d_ws;
    prep_params_k<<<(NV + 255) / 256, 256, 0, stream>>>(verts, params);
    gp_main_k<1><<<(TOTAL + 255) / 256, 256, 0, stream>>>(verts, f0, f1, f2, f3, params, out);
  } else {
    gp_main_k<2><<<(TOTAL + 255) / 256, 256, 0, stream>>>(verts, f0, f1, f2, f3, nullptr, out);
  }
}

// Round 9
// 202.736 us; speedup vs baseline: 1.1462x; 1.0003x over previous
//
#include <hip/hip_runtime.h>

// GraphProjection: out[N,963] = concat(verts[N,3], proj(f0)[N,64], proj(f1)[N,128],
//                                      proj(f2)[N,256], proj(f3)[N,512])
// Degenerate "bilinear": weights collapse to w11 = (x2-x1)*(y2-y1) in {0,1};
// every feature element is a masked gather of feat[c, floor(x), floor(y)].
//
// V9: wave-per-CONTIGUOUS-ROW-PAIR (the clean MLP probe).
//  - wave w handles rows {2w, 2w+1}: all ~9 gathers for BOTH rows issued
//    back-to-back (2x V5's outstanding loads), then 7.7 KB of contiguous
//    stores. Removes V6's confounds (row scatter, register bloat) and
//    V7's (LDS round-trip, barrier).
//  - params precomputed (3us prep kernel); row-pair params = 8 contiguous
//    ints -> one wave-uniform s_load_dwordx8.
//  - x4 grid anchored at col 3: boundaries {3,67,195,451} are ==3 (mod 4),
//    slice bases >=256B aligned -> all loads aligned dwordx4; pointers stay
//    in SGPRs (saddr-form loads), data VGPRs ~32 -> full occupancy.
//  - plain stores (NT measured -25us in V4).

static constexpr int NV      = 50000;
static constexpr int TOTAL   = 963 * NV;          // 48,150,000

// transposed feature sizes (floats): [S*S, C]
static constexpr int T0 = 56 * 56 * 64;   // 200,704
static constexpr int T1 = 28 * 28 * 128;  // 100,352
static constexpr int T2 = 14 * 14 * 256;  // 50,176
static constexpr int T3 = 7 * 7 * 512;    // 25,088
static constexpr int TSUM = T0 + T1 + T2 + T3; // 376,320
static constexpr int ZN   = 516;          // zero block (>=512 needed)

typedef float f32x4 __attribute__((ext_vector_type(4)));

__device__ __forceinline__ void store4_u(float* p, f32x4 v) {
  __builtin_memcpy(p, &v, 16);  // 4B-aligned dwordx4 store
}

__device__ __forceinline__ void proj_hw(const float* __restrict__ verts, int n,
                                        float& h, float& w) {
  float v0 = verts[3 * n + 0];
  float v1 = verts[3 * n + 1];
  float v2 = verts[3 * n + 2];
  // match numpy fp32 exactly: no FMA contraction, IEEE rn division
  h = __fadd_rn(__fmul_rn(248.0f, __fdiv_rn(v1, v2)), 111.5f);
  w = __fadd_rn(__fmul_rn(248.0f, __fdiv_rn(v0, -v2)), 111.5f);
  h = fminf(fmaxf(h, 0.0f), 223.0f);
  w = fminf(fmaxf(w, 0.0f), 223.0f);
}

__device__ __forceinline__ int level_off(float h, float w, float scale, int S) {
  float x = h * scale;  // scale = S/224 is an exact power of two
  float y = w * scale;
  int x1 = (int)floorf(x);
  int x2 = min((int)ceilf(x), S - 1);
  int y1 = (int)floorf(y);
  int y2 = min((int)ceilf(y), S - 1);
  return (x2 > x1 && y2 > y1) ? (x1 * S + y1) : -1;
}

__global__ __launch_bounds__(256) void prep_params_k(const float* __restrict__ verts,
                                                     int* __restrict__ params) {
  int n = blockIdx.x * 256 + threadIdx.x;
  if (n >= NV) return;
  float h, w;
  proj_hw(verts, n, h, w);
  params[4 * n + 0] = level_off(h, w, 0.25f,    56);
  params[4 * n + 1] = level_off(h, w, 0.125f,   28);
  params[4 * n + 2] = level_off(h, w, 0.0625f,  14);
  params[4 * n + 3] = level_off(h, w, 0.03125f, 7);
}

// [C,S,S] -> [S*S, C] so per-wave channel reads are contiguous; also zero-fills
// the ZN-float zero block used for out-of-image vertices.
__global__ __launch_bounds__(256) void transpose_k(
    const float* __restrict__ f0, const float* __restrict__ f1,
    const float* __restrict__ f2, const float* __restrict__ f3,
    float* __restrict__ t0, float* __restrict__ t1,
    float* __restrict__ t2, float* __restrict__ t3,
    float* __restrict__ zeros) {
  int i = blockIdx.x * 256 + threadIdx.x;
  if (i < T0) { int off = i >> 6, c = i & 63;  t0[i] = f0[c * 3136 + off]; return; }
  i -= T0;
  if (i < T1) { int off = i >> 7, c = i & 127; t1[i] = f1[c * 784 + off];  return; }
  i -= T1;
  if (i < T2) { int off = i >> 8, c = i & 255; t2[i] = f2[c * 196 + off];  return; }
  i -= T2;
  if (i < T3) { int off = i >> 9, c = i & 511; t3[i] = f3[c * 49 + off];   return; }
  i -= T3;
  if (i < ZN) zeros[i] = 0.0f;
}

struct RowS {
  const float* s0; const float* s1; const float* s2; const float* s3;
};

__device__ __forceinline__ RowS row_bases(
    int p0, int p1, int p2, int p3,
    const float* __restrict__ t0, const float* __restrict__ t1,
    const float* __restrict__ t2, const float* __restrict__ t3,
    const float* __restrict__ zeros) {
  // p<0 redirects into the zero block; offsets keep 16B alignment on the
  // x4 grid since (col - start_r) == 0 (mod 4).
  RowS r;
  r.s0 = ((p0 >= 0) ? t0 + (p0 << 6) : zeros) - 3;
  r.s1 = ((p1 >= 0) ? t1 + (p1 << 7) : zeros) - 67;
  r.s2 = ((p2 >= 0) ? t2 + (p2 << 8) : zeros) - 195;
  r.s3 = ((p3 >= 0) ? t3 + (p3 << 9) : zeros) - 451;
  return r;
}

// Wave-per-row-pair: 64 lanes copy rows {2w, 2w+1} (contiguous 7704 B of out).
// Cols [0,3)=verts, [3,67)=t0, [67,195)=t1, [195,451)=t2, [451,963)=t3.
__global__ __launch_bounds__(256) void gp_row2_k(
    const float* __restrict__ verts,
    const float* __restrict__ t0, const float* __restrict__ t1,
    const float* __restrict__ t2, const float* __restrict__ t3,
    const float* __restrict__ zeros,
    const int* __restrict__ params,
    float* __restrict__ out) {
  int wid  = (blockIdx.x * 256 + threadIdx.x) >> 6;
  int lane = threadIdx.x & 63;
  if (wid >= NV / 2) return;
  const int n0 = __builtin_amdgcn_readfirstlane(2 * wid);  // rows n0, n0+1

  // head elements for both rows (vector loads, issued first)
  float hva = 0.0f, hvb = 0.0f;
  if (lane < 3) {
    hva = verts[3 * n0 + lane];
    hvb = verts[3 * (n0 + 1) + lane];
  }

  // wave-uniform param fetch: 8 contiguous ints -> s_load_dwordx8
  int4 pva = *reinterpret_cast<const int4*>(params + 4 * n0);
  int4 pvb = *reinterpret_cast<const int4*>(params + 4 * n0 + 4);
  RowS A = row_bases(__builtin_amdgcn_readfirstlane(pva.x),
                     __builtin_amdgcn_readfirstlane(pva.y),
                     __builtin_amdgcn_readfirstlane(pva.z),
                     __builtin_amdgcn_readfirstlane(pva.w),
                     t0, t1, t2, t3, zeros);
  RowS B = row_bases(__builtin_amdgcn_readfirstlane(pvb.x),
                     __builtin_amdgcn_readfirstlane(pvb.y),
                     __builtin_amdgcn_readfirstlane(pvb.z),
                     __builtin_amdgcn_readfirstlane(pvb.w),
                     t0, t1, t2, t3, zeros);

  // all gathers for BOTH rows issued back-to-back (aligned dwordx4)
  int col0 = 3 + 4 * lane;            // [3,259): t0|t1|t2
  int col1 = 259 + 4 * lane;          // [259,515): t2|t3
  int col2 = 515 + 4 * lane;          // [515,771): t3
  int col3 = 771 + 4 * lane;          // [771,963) lane<48: t3
  const float* a0 = (lane < 16) ? A.s0 : (lane < 48) ? A.s1 : A.s2;
  const float* a1 = (lane < 48) ? A.s2 : A.s3;
  const float* b0 = (lane < 16) ? B.s0 : (lane < 48) ? B.s1 : B.s2;
  const float* b1 = (lane < 48) ? B.s2 : B.s3;

  f32x4 ra0 = *reinterpret_cast<const f32x4*>(a0 + col0);
  f32x4 ra1 = *reinterpret_cast<const f32x4*>(a1 + col1);
  f32x4 ra2 = *reinterpret_cast<const f32x4*>(A.s3 + col2);
  f32x4 ra3;
  if (lane < 48) ra3 = *reinterpret_cast<const f32x4*>(A.s3 + col3);
  f32x4 rb0 = *reinterpret_cast<const f32x4*>(b0 + col0);
  f32x4 rb1 = *reinterpret_cast<const f32x4*>(b1 + col1);
  f32x4 rb2 = *reinterpret_cast<const f32x4*>(B.s3 + col2);
  f32x4 rb3;
  if (lane < 48) rb3 = *reinterpret_cast<const f32x4*>(B.s3 + col3);

  // contiguous 2-row store burst
  float* oA = out + 963 * n0;
  float* oB = oA + 963;
  if (lane < 3) { oA[lane] = hva; oB[lane] = hvb; }
  store4_u(oA + col0, ra0);
  store4_u(oA + col1, ra1);
  store4_u(oA + col2, ra2);
  if (lane < 48) store4_u(oA + col3, ra3);
  store4_u(oB + col0, rb0);
  store4_u(oB + col1, rb1);
  store4_u(oB + col2, rb2);
  if (lane < 48) store4_u(oB + col3, rb3);
}

// ---------- fallback paths (small workspace) ----------
template <int MODE>
__device__ __forceinline__ int get_off(const int* __restrict__ params,
                                       const float* __restrict__ verts,
                                       int n, int k, float scale, int S) {
  if (MODE < 2) return params[4 * n + k];
  float h, w;
  proj_hw(verts, n, h, w);
  return level_off(h, w, scale, S);
}

static constexpr int B_VERTS = 3 * NV;            // 150,000
static constexpr int B_F0    = B_VERTS + 64 * NV; // 3,350,000
static constexpr int B_F1    = B_F0 + 128 * NV;   // 9,750,000
static constexpr int B_F2    = B_F1 + 256 * NV;   // 22,550,000

template <int MODE>
__global__ __launch_bounds__(256) void gp_main_k(
    const float* __restrict__ verts,
    const float* __restrict__ f0, const float* __restrict__ f1,
    const float* __restrict__ f2, const float* __restrict__ f3,
    const int* __restrict__ params, float* __restrict__ out) {
  int j = blockIdx.x * 256 + threadIdx.x;
  if (j >= TOTAL) return;

  if (j < B_VERTS) {
    int n = j / 3;
    int col = j - 3 * n;
    out[n * 963 + col] = verts[j];
    return;
  }

  int n, outcol;
  float val = 0.0f;
  if (j < B_F0) {
    int t = j - B_VERTS; n = t >> 6; int c = t & 63;
    int off = get_off<MODE>(params, verts, n, 0, 0.25f, 56);
    if (off >= 0) val = f0[c * 3136 + off];
    outcol = 3 + c;
  } else if (j < B_F1) {
    int t = j - B_F0; n = t >> 7; int c = t & 127;
    int off = get_off<MODE>(params, verts, n, 1, 0.125f, 28);
    if (off >= 0) val = f1[c * 784 + off];
    outcol = 67 + c;
  } else if (j < B_F2) {
    int t = j - B_F1; n = t >> 8; int c = t & 255;
    int off = get_off<MODE>(params, verts, n, 2, 0.0625f, 14);
    if (off >= 0) val = f2[c * 196 + off];
    outcol = 195 + c;
  } else {
    int t = j - B_F2; n = t >> 9; int c = t & 511;
    int off = get_off<MODE>(params, verts, n, 3, 0.03125f, 7);
    if (off >= 0) val = f3[c * 49 + off];
    outcol = 451 + c;
  }
  out[n * 963 + outcol] = val;
}

extern "C" void kernel_launch(void* const* d_in, const int* in_sizes, int n_in,
                              void* d_out, int out_size, void* d_ws, size_t ws_size,
                              hipStream_t stream) {
  const float* f0    = (const float*)d_in[0];
  const float* f1    = (const float*)d_in[1];
  const float* f2    = (const float*)d_in[2];
  const float* f3    = (const float*)d_in[3];
  const float* verts = (const float*)d_in[4];
  float* out = (float*)d_out;

  const size_t PARAM_BYTES = (size_t)NV * 4 * sizeof(int);  // 800,000 (16B-aligned)
  const size_t FULL_BYTES  = PARAM_BYTES + (size_t)(TSUM + ZN) * sizeof(float);

  if (ws_size >= FULL_BYTES) {
    int*   params = (int*)d_ws;
    float* t0 = (float*)((char*)d_ws + PARAM_BYTES);
    float* t1 = t0 + T0;
    float* t2 = t1 + T1;
    float* t3 = t2 + T2;
    float* zeros = t3 + T3;
    prep_params_k<<<(NV + 255) / 256, 256, 0, stream>>>(verts, params);
    transpose_k<<<(TSUM + ZN + 255) / 256, 256, 0, stream>>>(f0, f1, f2, f3,
                                                             t0, t1, t2, t3, zeros);
    const int pairBlocks = (NV / 2 * 64 + 255) / 256;  // 6,250 (wave per row pair)
    gp_row2_k<<<pairBlocks, 256, 0, stream>>>(verts, t0, t1, t2, t3, zeros, params, out);
  } else if (ws_size >= PARAM_BYTES) {
    int* params = (int*)d_ws;
    prep_params_k<<<(NV + 255) / 256, 256, 0, stream>>>(verts, params);
    gp_main_k<1><<<(TOTAL + 255) / 256, 256, 0, stream>>>(verts, f0, f1, f2, f3, params, out);
  } else {
    gp_main_k<2><<<(TOTAL + 255) / 256, 256, 0, stream>>>(verts, f0, f1, f2, f3, nullptr, out);
  }
}